// Round 3
// baseline (220.649 us; speedup 1.0000x reference)
//
#include <hip/hip_runtime.h>
#include <stdint.h>
#include <stddef.h>

// ---------------------------------------------------------------------------
// B=4, N=2048, D=768, H=12, HD=64. BN=8192.
// I/O fp32; internal bf16 MFMA + fp32 accum.
// qkv hidden [8192][2304] bf16 (Q 0..767 | K 768..1535 | V 1536..2303).
// V also materialized transposed: VT[(b*12+h)*64+d][2048 j] (aliases xb).
// Attention overwrites the Q region in place with merged-head output.
// attn v9: K/V tiles staged in MFMA-FRAGMENT ORDER: LDS slot (group,lane)
// holds exactly the 16B that lane reads for that fragment -> every frag
// ds_read_b128 is base + lane*16 (linear, zero bank conflicts, one address
// register + imm offsets). Staging via GLD16 with per-lane global source
// permuted to match. In-register softmax (swapped 32x32x16 QK^T,
// cvt_pk_bf16 + permlane32_swap) unchanged from v7/v8 (verified).
// 4 independent l-accumulators (no serial add chain); s_setprio around MFMA.
// ---------------------------------------------------------------------------

typedef __bf16 bf16x8 __attribute__((ext_vector_type(8)));
typedef float  f32x4  __attribute__((ext_vector_type(4)));
typedef float  f32x16 __attribute__((ext_vector_type(16)));
typedef unsigned int u32x2 __attribute__((ext_vector_type(2)));

__device__ __forceinline__ float bf2f(unsigned short u){
  union { unsigned int i; float f; } x; x.i = ((unsigned int)u) << 16; return x.f;
}
// round-half-up bf16
__device__ __forceinline__ unsigned short fast2bf(float f){
  union { float f; unsigned int i; } x; x.f = f;
  return (unsigned short)((x.i + 0x8000u) >> 16);
}
__device__ __forceinline__ unsigned int fbits(float f){
  union { float f; unsigned int i; } x; x.f = f; return x.i;
}
// single-instruction packed fp32->bf16 pair (RNE)
__device__ __forceinline__ unsigned int cvtpk_bf16(float lo, float hi){
  unsigned int r;
  asm("v_cvt_pk_bf16_f32 %0, %1, %2" : "=v"(r) : "v"(lo), "v"(hi));
  return r;
}
// v_permlane32_swap_b32: a' = {a.lo32lanes, b.lo32lanes}, b' = {a.hi, b.hi}
__device__ __forceinline__ void plswap32(unsigned int &a, unsigned int &b){
#if __has_builtin(__builtin_amdgcn_permlane32_swap)
  u32x2 r = __builtin_amdgcn_permlane32_swap(a, b, false, false);
  a = r.x; b = r.y;
#else
  asm volatile("v_permlane32_swap_b32 %0, %1" : "+v"(a), "+v"(b));
#endif
}

#if __has_builtin(__builtin_amdgcn_exp2f)
  #define EXP2F(x) __builtin_amdgcn_exp2f(x)
#else
  #define EXP2F(x) exp2f(x)
#endif

// async global->LDS, 16B per lane; LDS dest = wave-uniform base + lane*16.
#define GLD16(gp, lp) __builtin_amdgcn_global_load_lds( \
  (__attribute__((address_space(1))) void*)(uintptr_t)(gp), \
  (__attribute__((address_space(3))) void*)(unsigned int)(uintptr_t)(lp), 16, 0, 0)

// ---------------------------------------------------------------------------
__global__ void f32_to_bf16(const float* __restrict__ in,
                            unsigned short* __restrict__ out, int n){
  int i = (blockIdx.x * 256 + threadIdx.x) * 4;
  if(i < n){
    float4 v = *(const float4*)(in + i);
    ushort4 o;
    o.x = fast2bf(v.x); o.y = fast2bf(v.y); o.z = fast2bf(v.z); o.w = fast2bf(v.w);
    *(ushort4*)(out + i) = o;
  }
}

// ---------------------------------------------------------------------------
__global__ void transpose_f32_bf16(const float* __restrict__ W,
                                   unsigned short* __restrict__ Wt, int K, int N){
  __shared__ float tile[32][33];
  int n0 = blockIdx.x * 32, k0 = blockIdx.y * 32;
  int tx = threadIdx.x, ty = threadIdx.y;   // (32,8)
  for(int i = ty; i < 32; i += 8) tile[i][tx] = W[(size_t)(k0 + i) * N + (n0 + tx)];
  __syncthreads();
  for(int i = ty; i < 32; i += 8) Wt[(size_t)(n0 + i) * K + (k0 + tx)] = fast2bf(tile[tx][i]);
}

// ---------------------------------------------------------------------------
// V transpose: VT[(b*12+h)*64 + d][j] = qkv[b*2048+j][1536 + h*64 + d]
// ---------------------------------------------------------------------------
__global__ __launch_bounds__(256) void transpose_v(const unsigned short* __restrict__ qkv,
                                                   unsigned short* __restrict__ VT){
  __shared__ __align__(16) unsigned short Ts[64*72];
  const int t  = threadIdx.x;
  const int jt = blockIdx.x;        // 0..31
  const int bh = blockIdx.y;        // 0..47
  const int b = bh / 12, h = bh - b*12;
  const unsigned short* src = qkv + (size_t)(b*2048 + jt*64)*2304 + 1536 + h*64;
  #pragma unroll
  for(int c = t; c < 512; c += 256){
    int j = c >> 3, d0 = (c & 7) * 8;
    *(uint4*)&Ts[j*72 + d0] = *(const uint4*)(src + (size_t)j*2304 + d0);
  }
  __syncthreads();
  unsigned short* dst = VT + (size_t)bh*64*2048 + jt*64;
  #pragma unroll
  for(int c = t; c < 512; c += 256){
    int d = c >> 3, j0 = (c & 7) * 8;
    ushort4 lo, hi;
    lo.x = Ts[(j0+0)*72 + d]; lo.y = Ts[(j0+1)*72 + d];
    lo.z = Ts[(j0+2)*72 + d]; lo.w = Ts[(j0+3)*72 + d];
    hi.x = Ts[(j0+4)*72 + d]; hi.y = Ts[(j0+5)*72 + d];
    hi.z = Ts[(j0+6)*72 + d]; hi.w = Ts[(j0+7)*72 + d];
    *(ushort4*)(dst + (size_t)d*2048 + j0)     = lo;
    *(ushort4*)(dst + (size_t)d*2048 + j0 + 4) = hi;
  }
}

// ---------------------------------------------------------------------------
// MFMA GEMM-BT v2: C = A*Bt^T + bias. 128x128 tile, BK=32, DOUBLE-BUFFERED
// global_load_lds.
// ---------------------------------------------------------------------------
template<typename OT>
__global__ __launch_bounds__(256) void gemm_bt(const unsigned short* __restrict__ A,
                                               const unsigned short* __restrict__ Bt,
                                               const float* __restrict__ bias,
                                               OT* __restrict__ C,
                                               int M, int N, int K, int lda){
  __shared__ __align__(16) unsigned short As[2][128*32];
  __shared__ __align__(16) unsigned short Bs[2][128*32];
  const int tid  = threadIdx.x;
  const int lane = tid & 63, w = tid >> 6;
  const int m0 = blockIdx.y * 128, n0 = blockIdx.x * 128;

  f32x4 acc[4][4];
  #pragma unroll
  for(int i=0;i<4;i++)
    #pragma unroll
    for(int j=0;j<4;j++) acc[i][j] = (f32x4){0.f,0.f,0.f,0.f};

  const int c0 = w*64 + lane, c1 = c0 + 256;
  const unsigned short* Ag0 = A  + (size_t)(m0 + (c0>>2)) * lda + (c0&3)*8;
  const unsigned short* Ag1 = A  + (size_t)(m0 + (c1>>2)) * lda + (c1&3)*8;
  const unsigned short* Bg0 = Bt + (size_t)(n0 + (c0>>2)) * K   + (c0&3)*8;
  const unsigned short* Bg1 = Bt + (size_t)(n0 + (c1>>2)) * K   + (c1&3)*8;

  const int wm = w & 1, wn = w >> 1;
  const int quad = lane >> 4, l15 = lane & 15;

  // prologue: stage tile 0 into buffer 0
  GLD16(Ag0, As[0] +        w*512);
  GLD16(Ag1, As[0] + 2048 + w*512);
  GLD16(Bg0, Bs[0] +        w*512);
  GLD16(Bg1, Bs[0] + 2048 + w*512);

  int cur = 0;
  for(int kt = 0; kt < K; kt += 32){
    __syncthreads();               // drains GLD16(cur) for all waves
    if(kt + 32 < K){               // issue next tile into the other buffer
      int nx = cur ^ 1;
      GLD16(Ag0 + kt + 32, As[nx] +        w*512);
      GLD16(Ag1 + kt + 32, As[nx] + 2048 + w*512);
      GLD16(Bg0 + kt + 32, Bs[nx] +        w*512);
      GLD16(Bg1 + kt + 32, Bs[nx] + 2048 + w*512);
    }

    bf16x8 af[4], bfr[4];
    #pragma unroll
    for(int mt=0;mt<4;mt++) af[mt]  = *(const bf16x8*)&As[cur][(wm*64 + mt*16 + l15)*32 + quad*8];
    #pragma unroll
    for(int nt=0;nt<4;nt++) bfr[nt] = *(const bf16x8*)&Bs[cur][(wn*64 + nt*16 + l15)*32 + quad*8];
    #pragma unroll
    for(int mt=0;mt<4;mt++)
      #pragma unroll
      for(int nt=0;nt<4;nt++)
        acc[mt][nt] = __builtin_amdgcn_mfma_f32_16x16x32_bf16(af[mt], bfr[nt], acc[mt][nt], 0, 0, 0);
    cur ^= 1;
  }

  // epilogue: C/D layout col=lane&15, row=quad*4+reg
  #pragma unroll
  for(int nt=0;nt<4;nt++){
    int col = n0 + wn*64 + nt*16 + l15;
    float bv = bias[col];
    #pragma unroll
    for(int mt=0;mt<4;mt++){
      int row0 = m0 + wm*64 + mt*16 + quad*4;
      #pragma unroll
      for(int i=0;i<4;i++){
        float v = acc[mt][nt][i] + bv;
        if constexpr (sizeof(OT) == 2)
          C[(size_t)(row0 + i) * N + col] = (OT)fast2bf(v);
        else
          C[(size_t)(row0 + i) * N + col] = (OT)v;
      }
    }
  }
}

// ---------------------------------------------------------------------------
// MFMA flash attention v9 — fragment-order LDS staging, conflict-free reads.
//
// Block = 256 threads = 4 waves; wave w owns q-rows q0 = bx*128 + w*32.
// 1-D grid 768 blocks, XCD-clustered remap (16 blocks sharing (b,h) -> 1 XCD).
//
// LDS tile layout (per 64-k tile, 8KB each for K and V, double-buffered):
//   K slot (g = ks*4+c, lane):          K[kt + ks*32 + (lane&31)][c*16 + (lane>>5)*8 +0..7]
//   V slot (g = ks*4+khalf*2+dblk, lane): VT-row d=dblk*32+(lane&31), k-chunk
//                                         kt + ks*32 + khalf*16 + (lane>>5)*8 +0..7
// Each slot is the exact 16B fragment lane reads -> frag load = base+lane*16:
// linear wave pattern, ZERO bank conflicts, imm-offset addressing.
// Staging: 2 GLD16/wave/matrix, source = per-lane permuted global address.
// Per 32-k step: S^T = mfma(K,Q) x4 (q lane-local), p=exp2 (4 indep l-accums),
// P-frags via 8x cvt_pk_bf16 + 4x permlane32_swap, O += mfma(P,V) x4.
// s_setprio(1) around MFMA clusters. One barrier per 64-k tile.
// ---------------------------------------------------------------------------
__global__ __launch_bounds__(256, 3) void attn_mfma(unsigned short* __restrict__ qkv,
                                                    const unsigned short* __restrict__ VT){
  __shared__ __align__(16) unsigned short Ks[2][4096];   // 8KB frag-order
  __shared__ __align__(16) unsigned short Vs[2][4096];
  __shared__ float linv_lds[4*32];

  const int t    = threadIdx.x;
  const int lane = t & 63, w = t >> 6;
  const int l31  = lane & 31, hi = lane >> 5;

  // XCD-clustered bijective remap: 768 % 8 == 0.
  const int bid = blockIdx.x;
  const int wg  = (bid & 7) * 96 + (bid >> 3);
  const int b   = wg / 192;                   // 16*12 = 192
  const int rem = wg - b * 192;
  const int h   = rem >> 4;
  const int bx  = rem & 15;
  const int q0  = bx * 128 + w * 32;

  unsigned short* Qg = qkv + (size_t)(b*2048 + q0)*2304 + h*64;

  // ---- Q B-frags: qf[c] = Q[q=l31][d = c*16 + hi*8 + 0..7], pre-scaled ----
  const float QSCALE = 0.125f * 1.4426950408889634f;
  bf16x8 qf[4];
  #pragma unroll
  for(int c=0;c<4;c++){
    uint4 raw = *(const uint4*)(Qg + (size_t)l31*2304 + c*16 + hi*8);
    const unsigned short* rp = (const unsigned short*)&raw;
    unsigned short o[8];
    #pragma unroll
    for(int e=0;e<8;e++) o[e] = fast2bf(bf2f(rp[e]) * QSCALE);
    qf[c] = *(const bf16x8*)o;
  }

  f32x16 oacc0, oacc1;
  #pragma unroll
  for(int i=0;i<16;i++){ oacc0[i] = 0.f; oacc1[i] = 0.f; }
  float lp0=0.f, lp1=0.f, lp2=0.f, lp3=0.f;

  // ---- staging: wave w stages fragment-groups gA=w*2, gB=w*2+1 ----
  const int gA = w*2, gB = w*2 + 1;
  const unsigned short* gK = qkv + (size_t)(b*2048)*2304 + 768 + h*64;  // +kt*2304
  const unsigned short* gV = VT + (size_t)(b*12 + h)*64*2048;           // +kt
  // K group g: ks=g>>2, c=g&3; source row ks*32+l31, d-chunk c*16+hi*8
  const size_t kOffA = (size_t)((gA>>2)*32 + l31)*2304 + (gA&3)*16 + hi*8;
  const size_t kOffB = (size_t)((gB>>2)*32 + l31)*2304 + (gB&3)*16 + hi*8;
  // V group g: ks=g>>2, khalf=(g>>1)&1, dblk=g&1; VT row dblk*32+l31,
  // k-offset ks*32 + khalf*16 + hi*8
  const size_t vOffA = (size_t)((gA&1)*32 + l31)*2048 + (gA>>2)*32 + ((gA>>1)&1)*16 + hi*8;
  const size_t vOffB = (size_t)((gB&1)*32 + l31)*2048 + (gB>>2)*32 + ((gB>>1)&1)*16 + hi*8;

  // prologue: stage tile 0 into buffer 0
  GLD16(gK + kOffA, Ks[0] + gA*512);
  GLD16(gK + kOffB, Ks[0] + gB*512);
  GLD16(gV + vOffA, Vs[0] + gA*512);
  GLD16(gV + vOffB, Vs[0] + gB*512);

  int cur = 0;
  #pragma unroll 1
  for(int it = 0; it < 32; ++it){
    __syncthreads();               // buf[cur] staged (drains GLD16) for all waves
    if(it + 1 < 32){               // stage next 64-k tile into other buffer
      int nx = cur ^ 1;
      gK += (size_t)64*2304;
      gV += 64;
      GLD16(gK + kOffA, Ks[nx] + gA*512);
      GLD16(gK + kOffB, Ks[nx] + gB*512);
      GLD16(gV + vOffA, Vs[nx] + gA*512);
      GLD16(gV + vOffB, Vs[nx] + gB*512);
    }
    const unsigned short* Kst = Ks[cur] + lane*8;   // lane*16 bytes
    const unsigned short* Vst = Vs[cur] + lane*8;

    #pragma unroll
    for(int ks = 0; ks < 2; ++ks){
      // ---- K frags (linear reads, imm offsets) ----
      bf16x8 kf0 = *(const bf16x8*)(Kst + (ks*4 + 0)*512);
      bf16x8 kf1 = *(const bf16x8*)(Kst + (ks*4 + 1)*512);
      bf16x8 kf2 = *(const bf16x8*)(Kst + (ks*4 + 2)*512);
      bf16x8 kf3 = *(const bf16x8*)(Kst + (ks*4 + 3)*512);

      // ---- S^T tile: 32k x 32q ----
      f32x16 sacc;
      #pragma unroll
      for(int i=0;i<16;i++) sacc[i] = 0.f;
      __builtin_amdgcn_s_setprio(1);
      sacc = __builtin_amdgcn_mfma_f32_32x32x16_bf16(kf0, qf[0], sacc, 0, 0, 0);
      sacc = __builtin_amdgcn_mfma_f32_32x32x16_bf16(kf1, qf[1], sacc, 0, 0, 0);
      sacc = __builtin_amdgcn_mfma_f32_32x32x16_bf16(kf2, qf[2], sacc, 0, 0, 0);
      sacc = __builtin_amdgcn_mfma_f32_32x32x16_bf16(kf3, qf[3], sacc, 0, 0, 0);
      __builtin_amdgcn_s_setprio(0);

      // ---- V frags (linear reads; latency hides under exp/pack) ----
      bf16x8 vf00 = *(const bf16x8*)(Vst + (ks*4 + 0)*512);  // khalf0,dblk0
      bf16x8 vf01 = *(const bf16x8*)(Vst + (ks*4 + 1)*512);  // khalf0,dblk1
      bf16x8 vf10 = *(const bf16x8*)(Vst + (ks*4 + 2)*512);  // khalf1,dblk0
      bf16x8 vf11 = *(const bf16x8*)(Vst + (ks*4 + 3)*512);  // khalf1,dblk1

      // ---- softmax numerator: p = 2^sacc; 4 independent partial sums ----
      float p[16];
      #pragma unroll
      for(int r=0;r<16;r++) p[r] = EXP2F(sacc[r]);
      #pragma unroll
      for(int r=0;r<16;r+=4){
        lp0 += p[r]; lp1 += p[r+1]; lp2 += p[r+2]; lp3 += p[r+3];
      }

      // ---- P -> A-frags in-register (verified v7 pipeline) ----
      unsigned int d0 = cvtpk_bf16(p[0],  p[1]);
      unsigned int d1 = cvtpk_bf16(p[2],  p[3]);
      unsigned int d2 = cvtpk_bf16(p[4],  p[5]);
      unsigned int d3 = cvtpk_bf16(p[6],  p[7]);
      unsigned int d4 = cvtpk_bf16(p[8],  p[9]);
      unsigned int d5 = cvtpk_bf16(p[10], p[11]);
      unsigned int d6 = cvtpk_bf16(p[12], p[13]);
      unsigned int d7 = cvtpk_bf16(p[14], p[15]);
      plswap32(d0, d2); plswap32(d1, d3);          // chunk0: k = 8hi + 0..7
      plswap32(d4, d6); plswap32(d5, d7);          // chunk1: k = 16 + 8hi + 0..7
      unsigned int c0w[4] = {d0, d1, d2, d3};
      unsigned int c1w[4] = {d4, d5, d6, d7};
      bf16x8 pa0 = *(const bf16x8*)c0w;            // P[q=l31][k = hi*8+0..7]
      bf16x8 pa1 = *(const bf16x8*)c1w;            // P[q=l31][k = 16+hi*8+0..7]

      // ---- PV: O[32q x 64d] accumulate ----
      __builtin_amdgcn_s_setprio(1);
      oacc0 = __builtin_amdgcn_mfma_f32_32x32x16_bf16(pa0, vf00, oacc0, 0, 0, 0);
      oacc1 = __builtin_amdgcn_mfma_f32_32x32x16_bf16(pa0, vf01, oacc1, 0, 0, 0);
      oacc0 = __builtin_amdgcn_mfma_f32_32x32x16_bf16(pa1, vf10, oacc0, 0, 0, 0);
      oacc1 = __builtin_amdgcn_mfma_f32_32x32x16_bf16(pa1, vf11, oacc1, 0, 0, 0);
      __builtin_amdgcn_s_setprio(0);
    }
    cur ^= 1;
  }

  // ---- l: combine partials + hi-halves (lane l, l^32 share q=l31) ----
  float lpart = (lp0 + lp1) + (lp2 + lp3);
  lpart += __shfl_xor(lpart, 32, 64);
  if(lane < 32) linv_lds[w*32 + l31] = 1.0f / lpart;
  __syncthreads();

  // ---- epilogue: O row q=(r&3)+8(r>>2)+4hi, col d = dblk*32 + l31 ----
  #pragma unroll
  for(int r=0;r<16;r++){
    int qrow = (r&3) + 8*(r>>2) + 4*hi;
    float li = linv_lds[w*32 + qrow];
    unsigned short* row = Qg + (size_t)qrow*2304;
    row[l31]      = fast2bf(oacc0[r] * li);
    row[32 + l31] = fast2bf(oacc1[r] * li);
  }
}

// ---------------------------------------------------------------------------
extern "C" void kernel_launch(void* const* d_in, const int* in_sizes, int n_in,
                              void* d_out, int out_size, void* d_ws, size_t ws_size,
                              hipStream_t stream){
  const float* x      = (const float*)d_in[0];  // [8192][768]
  const float* w_qkv  = (const float*)d_in[1];  // [768][2304]
  const float* b_qkv  = (const float*)d_in[2];  // [2304]
  const float* w_proj = (const float*)d_in[3];  // [768][768]
  const float* b_proj = (const float*)d_in[4];  // [768]
  float* out = (float*)d_out;                   // [8192][768]

  unsigned short* xb      = (unsigned short*)d_ws;                   // [8192][768]
  unsigned short* Wt_qkv  = xb      + (size_t)8192*768;              // [2304][768]
  unsigned short* Wt_proj = Wt_qkv  + (size_t)2304*768;              // [768][768]
  unsigned short* qkvb    = Wt_proj + (size_t)768*768;               // [8192][2304]
  unsigned short* VT      = xb;   // aliases xb: xb dead after gemm1

  f32_to_bf16<<<(8192*768)/1024, 256, 0, stream>>>(x, xb, 8192*768);
  transpose_f32_bf16<<<dim3(72, 24), dim3(32, 8), 0, stream>>>(w_qkv,  Wt_qkv,  768, 2304);
  transpose_f32_bf16<<<dim3(24, 24), dim3(32, 8), 0, stream>>>(w_proj, Wt_proj, 768, 768);

  gemm_bt<unsigned short><<<dim3(2304/128, 8192/128), 256, 0, stream>>>(
      xb, Wt_qkv, b_qkv, qkvb, 8192, 2304, 768, 768);

  transpose_v<<<dim3(32, 48), 256, 0, stream>>>(qkvb, VT);

  attn_mfma<<<768, 256, 0, stream>>>(qkvb, VT);

  gemm_bt<float><<<dim3(768/128, 8192/128), 256, 0, stream>>>(
      qkvb, Wt_proj, b_proj, out, 8192, 768, 768, 2304);
}